// Round 15
// baseline (209.108 us; speedup 1.0000x reference)
//
#include <hip/hip_runtime.h>

#define BB 128
#define NN 8192
#define SS 100
#define KK 512
#define SPB 4                  // samples per block (2 pairs, pipelined)
#define SPLIT (SS / SPB)       // 25 chunks per batch row
#define NT 1024                // 16 waves
#define EPT 8                  // elements per thread per sample
#define CAND 256
#define NBIN 2048
#define NWAVE 16

#define GIDX(e) (((e) >> 2) * 4096 + tid * 4 + ((e) & 3))
#define LN2 0.69314718056f

// LDS-only barrier: waits DS ops but leaves global loads in flight
// (__syncthreads drains vmcnt(0) too — guide §5). sched_barrier stops the
// compiler hoisting LDS reads above the wait (guide rule #18).
__device__ __forceinline__ void lds_barrier() {
    asm volatile("s_waitcnt lgkmcnt(0)" ::: "memory");
    __builtin_amdgcn_s_barrier();
    __builtin_amdgcn_sched_barrier(0);
}

// q-key: q = (-ln(u+eps)+eps) * e^{-lg} = e^{-p}, monotone DECREASING in p.
// ONE transcendental per element-sample; e^{-lg} precomputed per logit.
__device__ __forceinline__ float q_of(float u, float elg) {
    const float w = fmaf(__builtin_amdgcn_logf(u + 1e-20f), -LN2, 1e-20f);
    return w * elg;
}

// Monotone bin map via float bits (sign|exp|mant7), flipped so HIGHER bin =
// HIGHER p. Window q in [2^-13,16) i.e. p in (-2.77, 9]; outside clamps and
// clamped bins stay exact via the in-bin rank loop (exact q compares).
__device__ __forceinline__ int bin_of(float q) {
    const int t = (int)(__float_as_uint(q) >> 16);
    int b = 16639 - t;
    b = b < 0 ? 0 : b;
    return b > 2047 ? 2047 : b;
}

// elg[i] = e^{-logits[i]} (one v_exp per logit, reused over 100 samples)
__global__ __launch_bounds__(256) void exp_kernel(
    const float* __restrict__ logits, float* __restrict__ elg) {
    const int i = blockIdx.x * 256 + threadIdx.x;
    const float4 v = reinterpret_cast<const float4*>(logits)[i];
    float4 o;
    o.x = __expf(-v.x); o.y = __expf(-v.y);
    o.z = __expf(-v.z); o.w = __expf(-v.w);
    reinterpret_cast<float4*>(elg)[i] = o;
}

// One block = (b, 4 samples as 2 pipelined pairs). 9 LDS barriers / block;
// pair-1 loads are issued during pair-0's histogram phase and survive all
// barriers (lgkmcnt-only waits) -> zero exposed latency for pair 1.
// MODE 0: packed 4-bit counts (u32/thread) -> ws. MODE 1: atomicAdd out.
template <int MODE>
__global__ __launch_bounds__(NT, 8) void gumbel_topk_kernel(
    const float* __restrict__ elg_or_logits,
    const float* __restrict__ uniform,
    unsigned* __restrict__ ws,
    float* __restrict__ out) {

    __shared__ __align__(16) int histA[NBIN];
    __shared__ __align__(16) int histB[NBIN];
    __shared__ float ckA[CAND];
    __shared__ int   ciA[CAND];
    __shared__ float ckB[CAND];
    __shared__ int   ciB[CAND];
    __shared__ int waveTotA[NWAVE], waveTotB[NWAVE];
    __shared__ int bselA, bkkA, bselB, bkkB;
    __shared__ int cntA[2], cntB[2];

    const int tid  = threadIdx.x;
    const int lane = tid & 63;
    const int wv   = tid >> 6;
    const int b    = blockIdx.x / SPLIT;
    const int ch   = blockIdx.x % SPLIT;

    const float* erow  = elg_or_logits + (size_t)b * NN;
    const float* u0row = uniform + ((size_t)b * SS + ch * SPB) * NN;

    // ---- pair-0 + elg loads issued upfront; in flight across s0
    float le[EPT], qA[EPT], qB[EPT], sA[EPT], sB[EPT];
#pragma unroll
    for (int j = 0; j < 2; ++j) {
        *reinterpret_cast<float4*>(&qA[j * 4]) =
            *reinterpret_cast<const float4*>(&u0row[j * 4096 + tid * 4]);
        *reinterpret_cast<float4*>(&qB[j * 4]) =
            *reinterpret_cast<const float4*>(&u0row[NN + j * 4096 + tid * 4]);
        *reinterpret_cast<float4*>(&le[j * 4]) =
            *reinterpret_cast<const float4*>(&erow[j * 4096 + tid * 4]);
    }
    if (MODE == 1) {
#pragma unroll
        for (int e = 0; e < EPT; ++e) le[e] = __expf(-le[e]);
    }

    // ---- init LDS: 4096 ints over 1024 threads = one int4 each
    if (tid < 512) *reinterpret_cast<int4*>(&histA[tid * 4]) = make_int4(0, 0, 0, 0);
    else           *reinterpret_cast<int4*>(&histB[(tid - 512) * 4]) = make_int4(0, 0, 0, 0);
    if (tid == 0) { cntA[0] = 0; cntA[1] = 0; cntB[0] = 0; cntB[1] = 0; }
    lds_barrier();                                        // s0

    unsigned bits4 = 0;   // 4-bit membership count per element (max 4)

#pragma unroll
    for (int pr = 0; pr < 2; ++pr) {
        // ---- transform (1 log/elem) + histogram; q stays live
#pragma unroll
        for (int e = 0; e < EPT; ++e) {
            qA[e] = q_of(qA[e], le[e]);
            qB[e] = q_of(qB[e], le[e]);
            atomicAdd(&histA[bin_of(qA[e])], 1);
            atomicAdd(&histB[bin_of(qB[e])], 1);
        }
        // ---- prefetch pair 1 while pair 0 runs its phases
        if (pr == 0) {
#pragma unroll
            for (int j = 0; j < 2; ++j) {
                *reinterpret_cast<float4*>(&sA[j * 4]) =
                    *reinterpret_cast<const float4*>(&u0row[2 * NN + j * 4096 + tid * 4]);
                *reinterpret_cast<float4*>(&sB[j * 4]) =
                    *reinterpret_cast<const float4*>(&u0row[3 * NN + j * 4096 + tid * 4]);
            }
        }
        lds_barrier();                                    // s1

        // ---- scan: read own 2 bins, RE-ZERO them (ready for next pair),
        // cross-wave suffix scan
        const int base = tid * 2;
        const int2 hA = *reinterpret_cast<const int2*>(&histA[base]);
        const int2 hB = *reinterpret_cast<const int2*>(&histB[base]);
        *reinterpret_cast<int2*>(&histA[base]) = make_int2(0, 0);
        *reinterpret_cast<int2*>(&histB[base]) = make_int2(0, 0);
        const int sumA = hA.x + hA.y, sumB = hB.x + hB.y;
        int sufA = sumA, sufB = sumB;
#pragma unroll
        for (int d = 1; d < 64; d <<= 1) {
            const int oA = __shfl_down(sufA, d);
            const int oB = __shfl_down(sufB, d);
            if (lane + d < 64) { sufA += oA; sufB += oB; }
        }
        if (lane == 0) { waveTotA[wv] = sufA; waveTotB[wv] = sufB; }
        lds_barrier();                                    // s2

        int cumA = sufA - sumA, cumB = sufB - sumB;
        for (int w2 = wv + 1; w2 < NWAVE; ++w2) { cumA += waveTotA[w2]; cumB += waveTotB[w2]; }
        if (cumA < KK && cumA + hA.y >= KK) { bselA = base + 1; bkkA = KK - cumA; }
        cumA += hA.y;
        if (cumA < KK && cumA + hA.x >= KK) { bselA = base;     bkkA = KK - cumA; }
        if (cumB < KK && cumB + hB.y >= KK) { bselB = base + 1; bkkB = KK - cumB; }
        cumB += hB.y;
        if (cumB < KK && cumB + hB.x >= KK) { bselB = base;     bkkB = KK - cumB; }
        lds_barrier();                                    // s3

        const int selA = bselA, kkA = bkkA;
        const int selB = bselB, kkB = bkkB;

        // ---- collect threshold-bin candidates (~3/sample; keys live)
#pragma unroll
        for (int e = 0; e < EPT; ++e) {
            if (bin_of(qA[e]) == selA) {
                const int pos = atomicAdd(&cntA[pr], 1);
                if (pos < CAND) { ckA[pos] = qA[e]; ciA[pos] = GIDX(e); }
            }
            if (bin_of(qB[e]) == selB) {
                const int pos = atomicAdd(&cntB[pr], 1);
                if (pos < CAND) { ckB[pos] = qB[e]; ciB[pos] = GIDX(e); }
            }
        }
        lds_barrier();                                    // s4

        // ---- membership: in-bin elements rank by (q asc = p desc, idx asc)
        const int cA = cntA[pr] < CAND ? cntA[pr] : CAND;
        const int cB = cntB[pr] < CAND ? cntB[pr] : CAND;
#pragma unroll
        for (int e = 0; e < EPT; ++e) {
            {
                const int bb = bin_of(qA[e]);
                if (bb > selA) {
                    bits4 += 1u << (4 * e);
                } else if (bb == selA) {
                    const float kl = qA[e]; const int il = GIDX(e);
                    int r = 0;
                    for (int j = 0; j < cA; ++j)
                        r += (ckA[j] < kl || (ckA[j] == kl && ciA[j] < il)) ? 1 : 0;
                    if (r < kkA) bits4 += 1u << (4 * e);
                }
            }
            {
                const int bb = bin_of(qB[e]);
                if (bb > selB) {
                    bits4 += 1u << (4 * e);
                } else if (bb == selB) {
                    const float kl = qB[e]; const int il = GIDX(e);
                    int r = 0;
                    for (int j = 0; j < cB; ++j)
                        r += (ckB[j] < kl || (ckB[j] == kl && ciB[j] < il)) ? 1 : 0;
                    if (r < kkB) bits4 += 1u << (4 * e);
                }
            }
        }
        // ---- rotate staged pair into place (registers only)
        if (pr == 0) {
#pragma unroll
            for (int e = 0; e < EPT; ++e) { qA[e] = sA[e]; qB[e] = sB[e]; }
        }
    }

    if (MODE == 0) {
        ws[(size_t)blockIdx.x * NT + tid] = bits4;
    } else {
        float* orow = out + (size_t)b * NN;
#pragma unroll
        for (int e = 0; e < EPT; ++e) {
            const unsigned c = (bits4 >> (4 * e)) & 15u;
            if (c) atomicAdd(orow + GIDX(e), (float)c * 0.01f);
        }
    }
}

// Sum 25 packed-4-bit partials per u32 position; field <= 4, sum <= 100.
__global__ __launch_bounds__(256) void reduce_kernel(
    const unsigned* __restrict__ ws, float* __restrict__ out) {
    const int g   = blockIdx.x * 256 + threadIdx.x;   // 0..131071
    const int b   = g >> 10;
    const int pos = g & 1023;
    int acc[8] = {0, 0, 0, 0, 0, 0, 0, 0};
    for (int ch = 0; ch < SPLIT; ++ch) {
        const unsigned w = ws[((size_t)(b * SPLIT + ch) << 10) + pos];
#pragma unroll
        for (int e = 0; e < 8; ++e) acc[e] += (w >> (4 * e)) & 15u;
    }
    float* ob = out + (size_t)b * NN;
    const float4 o0 = make_float4(acc[0] * 0.01f, acc[1] * 0.01f,
                                  acc[2] * 0.01f, acc[3] * 0.01f);
    const float4 o1 = make_float4(acc[4] * 0.01f, acc[5] * 0.01f,
                                  acc[6] * 0.01f, acc[7] * 0.01f);
    *reinterpret_cast<float4*>(&ob[pos * 4])        = o0;
    *reinterpret_cast<float4*>(&ob[4096 + pos * 4]) = o1;
}

extern "C" void kernel_launch(void* const* d_in, const int* in_sizes, int n_in,
                              void* d_out, int out_size, void* d_ws, size_t ws_size,
                              hipStream_t stream) {
    const float* logits  = (const float*)d_in[0];   // [128, 8192] f32
    const float* uniform = (const float*)d_in[1];   // [128, 100, 8192] f32
    float* out = (float*)d_out;                     // [128, 8192] f32

    const int grid = BB * SPLIT;                    // 3200 blocks
    const size_t elgBytes = (size_t)BB * NN * sizeof(float);       // 4 MB
    const size_t cntBytes = (size_t)grid * NT * sizeof(unsigned);  // 13.1 MB

    if (ws_size >= elgBytes + cntBytes) {
        float* elg = (float*)d_ws;
        unsigned* cnts = (unsigned*)((char*)d_ws + elgBytes);
        exp_kernel<<<(BB * NN / 4) / 256, 256, 0, stream>>>(logits, elg);
        gumbel_topk_kernel<0><<<grid, NT, 0, stream>>>(
            elg, uniform, cnts, nullptr);
        reduce_kernel<<<(BB * NN / 8) / 256, 256, 0, stream>>>(cnts, out);
    } else {
        hipMemsetAsync(out, 0, (size_t)out_size * sizeof(float), stream);
        gumbel_topk_kernel<1><<<grid, NT, 0, stream>>>(
            logits, uniform, nullptr, out);
    }
}